// Round 16
// baseline (365.043 us; speedup 1.0000x reference)
//
#include <hip/hip_runtime.h>

#define NN 50000
#define NE 800000
#define FD 128
#define FDH 64            // FD/2 packed bf16 pairs
#define FA 32
#define NG 128
#define EETOT (NE + NN)
#define NBLK ((NN + 255) / 256)   // 196 scan blocks
#define PK 8                      // pool partial slices per graph
#define FEPB 2048                 // fill/deg: edges per chunk
#define FNCH ((EETOT + FEPB - 1) / FEPB)
#define DNCH ((NE + FEPB - 1) / FEPB)
#define NPXCD 6250                // nodes per XCD-parity bin (8*6250 = 50000)

typedef __attribute__((ext_vector_type(8))) short short8;
typedef __attribute__((ext_vector_type(4))) float f32x4;

// ---------- bf16 helpers ----------
__device__ __forceinline__ float bfbits(unsigned short u) {
    return __uint_as_float(((unsigned int)u) << 16);
}
__device__ __forceinline__ float bflo(unsigned int p) { return __uint_as_float(p << 16); }
__device__ __forceinline__ float bfhi(unsigned int p) { return __uint_as_float(p & 0xffff0000u); }
__device__ __forceinline__ unsigned short f2bf(float f) {   // RNE
    unsigned int u = __float_as_uint(f);
    unsigned int r = u + 0x7FFFu + ((u >> 16) & 1u);
    return (unsigned short)(r >> 16);
}
__device__ __forceinline__ unsigned int packbf(float a, float b) {
    return (unsigned int)f2bf(a) | ((unsigned int)f2bf(b) << 16);
}
__device__ __forceinline__ int ld_idx(const int* p, int i, int is64) {
    return is64 ? p[2 * i] : p[i];
}
__device__ int probe_bf16(const unsigned int* t, int nwords) {
    int nz = 0, hits = 0;
    for (int i = 0; i < nwords; ++i) {
        unsigned int w = t[i];
        if (w == 0u) continue;
        ++nz;
        unsigned int e = (w >> 7) & 0xFFu;
        if (e >= 100u && e <= 140u) ++hits;
    }
    return (nz < 8) ? 1 : (hits * 4 >= nz * 3);
}

// ---------- sentinels ----------
__global__ __launch_bounds__(128) void mark_kernel(float* out, float v) {
    out[threadIdx.x] = v;
}

// ---------- all dtype probes once ----------
__global__ __launch_bounds__(64) void flags_kernel(
        const unsigned int* x, const int* ei, const int* batch,
        const unsigned int* addf, const unsigned int* w1, const unsigned int* b1,
        const unsigned int* w2, const unsigned int* b2, const unsigned int* fc1w,
        const unsigned int* fc1b, const unsigned int* fc2w, const unsigned int* fc2b,
        int* flags) {
    if (threadIdx.x != 0) return;
    flags[0]  = probe_bf16(x, 64);
    flags[3]  = probe_bf16(addf, 64);
    flags[4]  = probe_bf16(w1, 64);
    flags[5]  = probe_bf16(b1, 64);
    flags[6]  = probe_bf16(w2, 64);
    flags[7]  = probe_bf16(b2, 64);
    flags[8]  = probe_bf16(fc1w, 64);
    flags[9]  = probe_bf16(fc1b, 64);
    flags[10] = probe_bf16(fc2w, 64);
    flags[11] = probe_bf16(fc2b, 1);
    int odd_or = 0;
    for (int k = 0; k < 32; ++k) odd_or |= ei[2 * k + 1];
    flags[12] = (odd_or == 0) ? 1 : 0;
    flags[13] = (batch[NN - 1] == 0) ? 1 : 0;
}

// ---------- fused prep: canonicalize everything + zero degi ----------
__global__ __launch_bounds__(256) void prep(
        const void* x, const void* addf,
        const void* w1, const void* b1, const void* w2, const void* b2,
        const void* fc1w, const void* fc1b, const void* fc2w, const void* fc2b,
        unsigned int* bufC, unsigned int* W1t, unsigned int* W2t,
        float* addff, float* b1f, float* b2f, float* fc1wf, float* fc1bf,
        float* fc2wf, float* fc2bf, const int* flags, int* degi) {
    int b = blockIdx.x;
    if (b < 12500) {
        int i = b * 256 + threadIdx.x;           // < NN*FDH = 3.2M
        if (flags[0]) {
            bufC[i] = ((const unsigned int*)x)[i];
        } else {
            const float* s = (const float*)x;
            bufC[i] = packbf(s[2 * i], s[2 * i + 1]);
        }
    } else if (b < 12564) {
        int rel = (b - 12500) * 256 + threadIdx.x;   // [0,16384)
        const void* src = (rel < 8192) ? w1 : w2;
        unsigned int* dst = (rel < 8192) ? W1t : W2t;
        int flag = (rel < 8192) ? flags[4] : flags[6];
        int rr = rel & 8191;
        int n = rr >> 6, kk = rr & 63;
        float lo, hi;
        if (flag) {
            const unsigned short* s = (const unsigned short*)src;
            lo = bfbits(s[(2 * kk) * FD + n]);
            hi = bfbits(s[(2 * kk + 1) * FD + n]);
        } else {
            const float* s = (const float*)src;
            lo = s[(2 * kk) * FD + n];
            hi = s[(2 * kk + 1) * FD + n];
        }
        dst[rr] = packbf(lo, hi);
    } else if (b < 12663) {
        int i = (b - 12564) * 256 + threadIdx.x;     // [0,25344)
        const void* src; float* dst; int flag; int rel;
        if      (i < 4096)  { src = addf; dst = addff; flag = flags[3];  rel = i; }
        else if (i < 4224)  { src = b1;   dst = b1f;   flag = flags[5];  rel = i - 4096; }
        else if (i < 4352)  { src = b2;   dst = b2f;   flag = flags[7];  rel = i - 4224; }
        else if (i < 24832) { src = fc1w; dst = fc1wf; flag = flags[8];  rel = i - 4352; }
        else if (i < 24960) { src = fc1b; dst = fc1bf; flag = flags[9];  rel = i - 24832; }
        else if (i < 25216) { src = fc2w; dst = fc2wf; flag = flags[10]; rel = i - 24960; }
        else if (i < 25218) { src = fc2b; dst = fc2bf; flag = flags[11]; rel = i - 25216; }
        else return;
        if (flag) dst[rel] = bfbits(((const unsigned short*)src)[rel]);
        else      dst[rel] = ((const float*)src)[rel];
    } else {
        int i = (b - 12663) * 256 + threadIdx.x;
        if (i < NN) degi[i] = 0;
    }
}

// ---------- degree with XCD-affinity dst binning ----------
__global__ __launch_bounds__(256) void deg_kernel(const int* ei, const int* flags,
                                                  int* deg) {
    int chunk = blockIdx.x >> 3;
    int par   = blockIdx.x & 7;
    int base  = chunk * FEPB;
    int is64  = flags[12];
    #pragma unroll
    for (int k = 0; k < FEPB / 256; ++k) {
        int e = base + k * 256 + threadIdx.x;
        if (e >= NE) break;
        int d = ld_idx(ei, NE + e, is64);
        if (d / NPXCD != par) continue;
        atomicAdd(&deg[d], 1);
    }
}

// ---------- scan phase 1 (+ dinv fused) ----------
__global__ __launch_bounds__(256) void scan1(const int* deg, float* dinv,
                                             int* escan, int* bsum) {
    __shared__ int sh[256];
    int i = blockIdx.x * 256 + threadIdx.x;
    int d = (i < NN) ? deg[i] : 0;
    if (i < NN) dinv[i] = rsqrtf((float)(d + 1));
    int v = (i < NN) ? d + 1 : 0;
    sh[threadIdx.x] = v;
    __syncthreads();
    for (int off = 1; off < 256; off <<= 1) {
        int a = ((int)threadIdx.x >= off) ? sh[threadIdx.x - off] : 0;
        __syncthreads();
        sh[threadIdx.x] += a;
        __syncthreads();
    }
    if (i < NN) escan[i] = sh[threadIdx.x] - v;
    if (threadIdx.x == 255) bsum[blockIdx.x] = sh[255];
}

// ---------- scan phase 2+3 + gstart fused ----------
__global__ __launch_bounds__(256) void scan3(const int* escan, const int* bsum,
        const int* batch, const int* flags, int* rowstart, int* cursor, int* gstart) {
    __shared__ int sb[256];
    int t = threadIdx.x;
    int v = (t < NBLK) ? bsum[t] : 0;
    sb[t] = v;
    __syncthreads();
    for (int off = 1; off < 256; off <<= 1) {
        int a = (t >= off) ? sb[t - off] : 0;
        __syncthreads();
        sb[t] += a;
        __syncthreads();
    }
    int boff = (blockIdx.x == 0) ? 0 : sb[blockIdx.x - 1];
    int i = blockIdx.x * 256 + t;
    if (i < NN) {
        int r = escan[i] + boff;
        rowstart[i] = r;
        cursor[i]   = r;
    }
    if (i == 0) rowstart[NN] = EETOT;
    if (i < NN) {
        int is64 = flags[13];
        int bc = ld_idx(batch, i, is64);
        if (i == 0) {
            for (int g = 0; g <= bc; ++g) gstart[g] = 0;
        } else {
            int bp = ld_idx(batch, i - 1, is64);
            for (int g = bp + 1; g <= bc; ++g) gstart[g] = i;
        }
        if (i == NN - 1) {
            for (int g = bc + 1; g <= NG; ++g) gstart[g] = NN;
        }
    }
}

// ---------- CSR fill with XCD-affinity dst binning ----------
__global__ __launch_bounds__(256) void fill_kernel(const int* ei, const int* flags,
        const float* dinv, int* cursor, unsigned int* cv) {
    int chunk = blockIdx.x >> 3;
    int par   = blockIdx.x & 7;
    int base  = chunk * FEPB;
    int is64  = flags[12];
    #pragma unroll
    for (int k = 0; k < FEPB / 256; ++k) {
        int e = base + k * 256 + threadIdx.x;
        if (e >= EETOT) break;
        int s, d;
        if (e < NE) { d = ld_idx(ei, NE + e, is64); s = -1; }
        else        { s = d = e - NE; }
        if (d / NPXCD != par) continue;
        if (s < 0) s = ld_idx(ei, e, is64);
        int pos = atomicAdd(&cursor[d], 1);
        cv[pos] = (unsigned int)s | ((unsigned int)f2bf(dinv[s] * dinv[d]) << 16);
    }
}

// ---------- MFMA GEMM: C[NN][128] = A[NN][128] @ W[128][128], all bf16 ----------
__global__ __launch_bounds__(256) void gemm_mfma(const unsigned int* __restrict__ A,
        const unsigned int* __restrict__ Wt, unsigned short* __restrict__ C) {
    int wave = threadIdx.x >> 6;
    int lane = threadIdx.x & 63;
    int quad = lane >> 4;
    int l16  = lane & 15;
    int mbase = blockIdx.x * 64 + wave * 16;
    int ra = mbase + l16;
    if (ra >= NN) ra = NN - 1;
    short8 af[4];
    const uint4* Arow = (const uint4*)(A + (size_t)ra * FDH);
    #pragma unroll
    for (int kk = 0; kk < 4; ++kk) {
        uint4 v = Arow[kk * 4 + quad];
        af[kk] = *(short8*)&v;
    }
    #pragma unroll
    for (int nt = 0; nt < 8; ++nt) {
        int n = nt * 16 + l16;
        const uint4* Wrow = (const uint4*)(Wt + (size_t)n * FDH);
        f32x4 acc = {0.f, 0.f, 0.f, 0.f};
        #pragma unroll
        for (int kk = 0; kk < 4; ++kk) {
            uint4 wv = Wrow[kk * 4 + quad];
            short8 bf = *(short8*)&wv;
            acc = __builtin_amdgcn_mfma_f32_16x16x32_bf16(af[kk], bf, acc, 0, 0, 0);
        }
        int row0 = mbase + quad * 4;
        #pragma unroll
        for (int reg = 0; reg < 4; ++reg) {
            int r = row0 + reg;
            if (r < NN) C[(size_t)r * FD + nt * 16 + l16] = f2bf(acc[reg]);
        }
    }
}

// ---------- CSR aggregation: 2 waves per node (split edge range) + LDS combine ----------
__global__ __launch_bounds__(256) void aggregate_kernel(const unsigned int* Hb,
        const unsigned int* cv, const int* rowstart, const float* bias,
        unsigned int* outb) {
    __shared__ float lds[2 * FD];
    int tid  = threadIdx.x;
    int node = tid >> 7;          // 0,1
    int half = (tid >> 6) & 1;    // 0,1
    int cp   = tid & 63;
    int n = blockIdx.x * 2 + node;      // NN even, grid exact
    int jb = rowstart[n], je = rowstart[n + 1];
    int mid = jb + ((je - jb + 1) >> 1);
    int j  = half ? mid : jb;
    int j1 = half ? je  : mid;
    float acc0 = 0.f, acc1 = 0.f;
    for (; j + 7 < j1; j += 8) {
        unsigned int rr[8], hh[8];
        #pragma unroll
        for (int k = 0; k < 8; ++k) rr[k] = cv[j + k];
        #pragma unroll
        for (int k = 0; k < 8; ++k) hh[k] = Hb[(size_t)(rr[k] & 0xFFFFu) * FDH + cp];
        #pragma unroll
        for (int k = 0; k < 8; ++k) {
            float v = bfbits((unsigned short)(rr[k] >> 16));
            acc0 += v * bflo(hh[k]);
            acc1 += v * bfhi(hh[k]);
        }
    }
    for (; j + 3 < j1; j += 4) {
        unsigned int rr[4], hh[4];
        #pragma unroll
        for (int k = 0; k < 4; ++k) rr[k] = cv[j + k];
        #pragma unroll
        for (int k = 0; k < 4; ++k) hh[k] = Hb[(size_t)(rr[k] & 0xFFFFu) * FDH + cp];
        #pragma unroll
        for (int k = 0; k < 4; ++k) {
            float v = bfbits((unsigned short)(rr[k] >> 16));
            acc0 += v * bflo(hh[k]);
            acc1 += v * bfhi(hh[k]);
        }
    }
    for (; j < j1; ++j) {
        unsigned int r = cv[j];
        unsigned int h = Hb[(size_t)(r & 0xFFFFu) * FDH + cp];
        float v = bfbits((unsigned short)(r >> 16));
        acc0 += v * bflo(h);
        acc1 += v * bfhi(h);
    }
    if (half) {
        lds[node * FD + 2 * cp]     = acc0;
        lds[node * FD + 2 * cp + 1] = acc1;
    }
    __syncthreads();
    if (!half) {
        acc0 += lds[node * FD + 2 * cp];
        acc1 += lds[node * FD + 2 * cp + 1];
        acc0 = fmaxf(acc0 + bias[2 * cp], 0.f);
        acc1 = fmaxf(acc1 + bias[2 * cp + 1], 0.f);
        outb[(size_t)n * FDH + cp] = packbf(acc0, acc1);
    }
}

// ---------- pool partials: 8 slices per graph ----------
__global__ __launch_bounds__(64) void pool_part(const unsigned int* Hb,
        const int* gstart, float* part) {
    int g = blockIdx.x >> 3;
    int k = blockIdx.x & (PK - 1);
    int cp = threadIdx.x;
    int s = gstart[g], e = gstart[g + 1];
    int len = e - s;
    int per = (len + PK - 1) / PK;
    int ss = s + k * per;
    int ee = ss + per; if (ee > e) ee = e;
    float a0 = 0.f, a1 = 0.f, b0 = 0.f, b1 = 0.f;
    int n = ss;
    for (; n + 1 < ee; n += 2) {
        unsigned int h0 = Hb[(size_t)n * FDH + cp];
        unsigned int h1 = Hb[(size_t)(n + 1) * FDH + cp];
        a0 += bflo(h0); a1 += bfhi(h0);
        b0 += bflo(h1); b1 += bfhi(h1);
    }
    if (n < ee) {
        unsigned int h0 = Hb[(size_t)n * FDH + cp];
        a0 += bflo(h0); a1 += bfhi(h0);
    }
    part[(size_t)(g * PK + k) * FD + 2 * cp]     = a0 + b0;
    part[(size_t)(g * PK + k) * FD + 2 * cp + 1] = a1 + b1;
}

// ---------- head (+ partial reduce fused) ----------
__global__ __launch_bounds__(128) void head_kernel(const float* part, const int* gstart,
        const float* addf, const float* fc1w, const float* fc1b,
        const float* fc2w, const float* fc2b, const int* flags, void* outp) {
    int g = blockIdx.x;
    int t = threadIdx.x;
    __shared__ float z[FD + FA];
    __shared__ float h[FD];
    float a = 0.f;
    #pragma unroll
    for (int k = 0; k < PK; ++k) a += part[(size_t)(g * PK + k) * FD + t];
    float cnt = (float)(gstart[g + 1] - gstart[g]);
    if (cnt < 1.0f) cnt = 1.0f;
    z[t] = a / cnt;
    if (t < FA) z[FD + t] = addf[g * FA + t];
    __syncthreads();
    float acc = fc1b[t];
    #pragma unroll 4
    for (int k = 0; k < FD + FA; ++k)
        acc += z[k] * fc1w[k * FD + t];
    h[t] = fmaxf(acc, 0.f);
    __syncthreads();
    if (t < 2) {
        float o = fc2b[t];
        for (int j = 0; j < FD; ++j) o += h[j] * fc2w[j * 2 + t];
        if (flags[0]) ((unsigned short*)outp)[g * 2 + t] = f2bf(o);
        else          ((float*)outp)[g * 2 + t] = o;
    }
}

extern "C" void kernel_launch(void* const* d_in, const int* in_sizes, int n_in,
                              void* d_out, int out_size, void* d_ws, size_t ws_size,
                              hipStream_t stream) {
    (void)out_size;

    if (n_in != 12) {
        hipLaunchKernelGGL(mark_kernel, dim3(1), dim3(128), 0, stream,
                           (float*)d_out, 2000.0f);
        return;
    }
    const int exp_sizes[12] = {6400000, 1600000, 50000, 4096, 16384, 128,
                               16384, 128, 20480, 128, 256, 2};
    for (int i = 0; i < 12; ++i) {
        if (in_sizes[i] != exp_sizes[i]) {
            hipLaunchKernelGGL(mark_kernel, dim3(1), dim3(128), 0, stream,
                               (float*)d_out, 3000.0f + 100.0f * i);
            return;
        }
    }

    size_t off = 0;
    char* base = (char*)d_ws;
#define WSALLOC(ptr, type, nbytes) \
    type* ptr = (type*)(base + off); off += (((size_t)(nbytes)) + 255) & ~(size_t)255;
    WSALLOC(bufA,  unsigned int, (size_t)NN * FDH * 4)
    WSALLOC(bufB,  unsigned int, (size_t)NN * FDH * 4)
    WSALLOC(bufC,  unsigned int, (size_t)NN * FDH * 4)
    WSALLOC(dinv,  float, (size_t)NN * 4)
    WSALLOC(degi,  int,   (size_t)NN * 4)
    WSALLOC(rowst, int,   (size_t)(NN + 1) * 4)
    WSALLOC(cursor,int,   (size_t)NN * 4)
    WSALLOC(escan, int,   (size_t)NN * 4)
    WSALLOC(bsum,  int,   (size_t)NBLK * 4)
    WSALLOC(cv,    unsigned int, (size_t)EETOT * 4)
    WSALLOC(part,  float, (size_t)NG * PK * FD * 4)
    WSALLOC(gstart,int,   (size_t)(NG + 1) * 4)
    WSALLOC(W1t,   unsigned int, (size_t)FD * FDH * 4)
    WSALLOC(W2t,   unsigned int, (size_t)FD * FDH * 4)
    WSALLOC(b1f,   float, FD * 4)
    WSALLOC(b2f,   float, FD * 4)
    WSALLOC(addff, float, (size_t)NG * FA * 4)
    WSALLOC(fc1wf, float, (size_t)(FD + FA) * FD * 4)
    WSALLOC(fc1bf, float, FD * 4)
    WSALLOC(fc2wf, float, FD * 2 * 4)
    WSALLOC(fc2bf, float, 2 * 4)
    WSALLOC(flags, int, 16 * 4)
#undef WSALLOC
    if (ws_size < off) {
        hipLaunchKernelGGL(mark_kernel, dim3(1), dim3(128), 0, stream,
                           (float*)d_out, 1000.0f);
        return;
    }

    const int* ei    = (const int*)d_in[1];
    const int* batch = (const int*)d_in[2];

    hipLaunchKernelGGL(flags_kernel, dim3(1), dim3(64), 0, stream,
                       (const unsigned int*)d_in[0], ei, batch,
                       (const unsigned int*)d_in[3], (const unsigned int*)d_in[4],
                       (const unsigned int*)d_in[5], (const unsigned int*)d_in[6],
                       (const unsigned int*)d_in[7], (const unsigned int*)d_in[8],
                       (const unsigned int*)d_in[9], (const unsigned int*)d_in[10],
                       (const unsigned int*)d_in[11], flags);

    hipLaunchKernelGGL(prep, dim3(12859), dim3(256), 0, stream,
                       d_in[0], d_in[3], d_in[4], d_in[5], d_in[6],
                       d_in[7], d_in[8], d_in[9], d_in[10], d_in[11],
                       bufC, W1t, W2t, addff, b1f, b2f, fc1wf, fc1bf,
                       fc2wf, fc2bf, flags, degi);

    hipLaunchKernelGGL(deg_kernel, dim3(DNCH * 8), dim3(256), 0, stream,
                       ei, flags, degi);
    hipLaunchKernelGGL(scan1, dim3(NBLK), dim3(256), 0, stream,
                       degi, dinv, escan, bsum);
    hipLaunchKernelGGL(scan3, dim3(NBLK), dim3(256), 0, stream,
                       escan, bsum, batch, flags, rowst, cursor, gstart);
    hipLaunchKernelGGL(fill_kernel, dim3(FNCH * 8), dim3(256), 0, stream,
                       ei, flags, dinv, cursor, cv);

    hipLaunchKernelGGL(gemm_mfma, dim3((NN + 63) / 64), dim3(256), 0, stream,
                       bufC, W1t, (unsigned short*)bufA);
    hipLaunchKernelGGL(aggregate_kernel, dim3(NN / 2), dim3(256), 0, stream,
                       bufA, cv, rowst, b1f, bufB);
    hipLaunchKernelGGL(gemm_mfma, dim3((NN + 63) / 64), dim3(256), 0, stream,
                       bufB, W2t, (unsigned short*)bufA);
    hipLaunchKernelGGL(aggregate_kernel, dim3(NN / 2), dim3(256), 0, stream,
                       bufA, cv, rowst, b2f, bufB);

    hipLaunchKernelGGL(pool_part, dim3(NG * PK), dim3(64), 0, stream,
                       bufB, gstart, part);
    hipLaunchKernelGGL(head_kernel, dim3(NG), dim3(FD), 0, stream,
                       part, gstart, addff, fc1wf, fc1bf, fc2wf, fc2bf,
                       flags, d_out);
}

// Round 17
// 338.474 us; speedup vs baseline: 1.0785x; 1.0785x over previous
//
#include <hip/hip_runtime.h>

#define NN 50000
#define NE 800000
#define FD 128
#define FDH 64            // FD/2 packed bf16 pairs
#define FA 32
#define NG 128
#define EETOT (NE + NN)
#define NBLK ((NN + 255) / 256)   // 196 scan blocks
#define PK 8                      // pool partial slices per graph
#define FEPB 2048                 // fill: edges per chunk
#define FNCH ((EETOT + FEPB - 1) / FEPB)
#define NPXCD 6250                // nodes per XCD-parity bin (8*6250 = 50000)

typedef __attribute__((ext_vector_type(8))) short short8;
typedef __attribute__((ext_vector_type(4))) float f32x4;

// ---------- bf16 helpers ----------
__device__ __forceinline__ float bfbits(unsigned short u) {
    return __uint_as_float(((unsigned int)u) << 16);
}
__device__ __forceinline__ float bflo(unsigned int p) { return __uint_as_float(p << 16); }
__device__ __forceinline__ float bfhi(unsigned int p) { return __uint_as_float(p & 0xffff0000u); }
__device__ __forceinline__ unsigned short f2bf(float f) {   // RNE
    unsigned int u = __float_as_uint(f);
    unsigned int r = u + 0x7FFFu + ((u >> 16) & 1u);
    return (unsigned short)(r >> 16);
}
__device__ __forceinline__ unsigned int packbf(float a, float b) {
    return (unsigned int)f2bf(a) | ((unsigned int)f2bf(b) << 16);
}
__device__ __forceinline__ int ld_idx(const int* p, int i, int is64) {
    return is64 ? p[2 * i] : p[i];
}
__device__ int probe_bf16(const unsigned int* t, int nwords) {
    int nz = 0, hits = 0;
    for (int i = 0; i < nwords; ++i) {
        unsigned int w = t[i];
        if (w == 0u) continue;
        ++nz;
        unsigned int e = (w >> 7) & 0xFFu;
        if (e >= 100u && e <= 140u) ++hits;
    }
    return (nz < 8) ? 1 : (hits * 4 >= nz * 3);
}

// ---------- sentinels ----------
__global__ __launch_bounds__(128) void mark_kernel(float* out, float v) {
    out[threadIdx.x] = v;
}

// ---------- all dtype probes once ----------
__global__ __launch_bounds__(64) void flags_kernel(
        const unsigned int* x, const int* ei, const int* batch,
        const unsigned int* addf, const unsigned int* w1, const unsigned int* b1,
        const unsigned int* w2, const unsigned int* b2, const unsigned int* fc1w,
        const unsigned int* fc1b, const unsigned int* fc2w, const unsigned int* fc2b,
        int* flags) {
    if (threadIdx.x != 0) return;
    flags[0]  = probe_bf16(x, 64);
    flags[3]  = probe_bf16(addf, 64);
    flags[4]  = probe_bf16(w1, 64);
    flags[5]  = probe_bf16(b1, 64);
    flags[6]  = probe_bf16(w2, 64);
    flags[7]  = probe_bf16(b2, 64);
    flags[8]  = probe_bf16(fc1w, 64);
    flags[9]  = probe_bf16(fc1b, 64);
    flags[10] = probe_bf16(fc2w, 64);
    flags[11] = probe_bf16(fc2b, 1);
    int odd_or = 0;
    for (int k = 0; k < 32; ++k) odd_or |= ei[2 * k + 1];
    flags[12] = (odd_or == 0) ? 1 : 0;
    flags[13] = (batch[NN - 1] == 0) ? 1 : 0;
}

// ---------- fused prep: canonicalize everything + zero degi ----------
__global__ __launch_bounds__(256) void prep(
        const void* x, const void* addf,
        const void* w1, const void* b1, const void* w2, const void* b2,
        const void* fc1w, const void* fc1b, const void* fc2w, const void* fc2b,
        unsigned int* bufC, unsigned int* W1t, unsigned int* W2t,
        float* addff, float* b1f, float* b2f, float* fc1wf, float* fc1bf,
        float* fc2wf, float* fc2bf, const int* flags, int* degi) {
    int b = blockIdx.x;
    if (b < 12500) {
        int i = b * 256 + threadIdx.x;           // < NN*FDH = 3.2M
        if (flags[0]) {
            bufC[i] = ((const unsigned int*)x)[i];
        } else {
            const float* s = (const float*)x;
            bufC[i] = packbf(s[2 * i], s[2 * i + 1]);
        }
    } else if (b < 12564) {
        int rel = (b - 12500) * 256 + threadIdx.x;   // [0,16384)
        const void* src = (rel < 8192) ? w1 : w2;
        unsigned int* dst = (rel < 8192) ? W1t : W2t;
        int flag = (rel < 8192) ? flags[4] : flags[6];
        int rr = rel & 8191;
        int n = rr >> 6, kk = rr & 63;
        float lo, hi;
        if (flag) {
            const unsigned short* s = (const unsigned short*)src;
            lo = bfbits(s[(2 * kk) * FD + n]);
            hi = bfbits(s[(2 * kk + 1) * FD + n]);
        } else {
            const float* s = (const float*)src;
            lo = s[(2 * kk) * FD + n];
            hi = s[(2 * kk + 1) * FD + n];
        }
        dst[rr] = packbf(lo, hi);
    } else if (b < 12663) {
        int i = (b - 12564) * 256 + threadIdx.x;     // [0,25344)
        const void* src; float* dst; int flag; int rel;
        if      (i < 4096)  { src = addf; dst = addff; flag = flags[3];  rel = i; }
        else if (i < 4224)  { src = b1;   dst = b1f;   flag = flags[5];  rel = i - 4096; }
        else if (i < 4352)  { src = b2;   dst = b2f;   flag = flags[7];  rel = i - 4224; }
        else if (i < 24832) { src = fc1w; dst = fc1wf; flag = flags[8];  rel = i - 4352; }
        else if (i < 24960) { src = fc1b; dst = fc1bf; flag = flags[9];  rel = i - 24832; }
        else if (i < 25216) { src = fc2w; dst = fc2wf; flag = flags[10]; rel = i - 24960; }
        else if (i < 25218) { src = fc2b; dst = fc2bf; flag = flags[11]; rel = i - 25216; }
        else return;
        if (flag) dst[rel] = bfbits(((const unsigned short*)src)[rel]);
        else      dst[rel] = ((const float*)src)[rel];
    } else {
        int i = (b - 12663) * 256 + threadIdx.x;
        if (i < NN) degi[i] = 0;
    }
}

// ---------- degree (plain atomics; HW coalesces per-wave) ----------
__global__ __launch_bounds__(256) void deg_kernel(const int* ei, const int* flags,
                                                  int* deg) {
    int e = blockIdx.x * 256 + threadIdx.x;
    int is64 = flags[12];
    if (e < NE) atomicAdd(&deg[ld_idx(ei, NE + e, is64)], 1);
}

// ---------- scan phase 1 (+ dinv fused) ----------
__global__ __launch_bounds__(256) void scan1(const int* deg, float* dinv,
                                             int* escan, int* bsum) {
    __shared__ int sh[256];
    int i = blockIdx.x * 256 + threadIdx.x;
    int d = (i < NN) ? deg[i] : 0;
    if (i < NN) dinv[i] = rsqrtf((float)(d + 1));
    int v = (i < NN) ? d + 1 : 0;
    sh[threadIdx.x] = v;
    __syncthreads();
    for (int off = 1; off < 256; off <<= 1) {
        int a = ((int)threadIdx.x >= off) ? sh[threadIdx.x - off] : 0;
        __syncthreads();
        sh[threadIdx.x] += a;
        __syncthreads();
    }
    if (i < NN) escan[i] = sh[threadIdx.x] - v;
    if (threadIdx.x == 255) bsum[blockIdx.x] = sh[255];
}

// ---------- scan phase 2+3 + gstart fused ----------
__global__ __launch_bounds__(256) void scan3(const int* escan, const int* bsum,
        const int* batch, const int* flags, int* rowstart, int* cursor, int* gstart) {
    __shared__ int sb[256];
    int t = threadIdx.x;
    int v = (t < NBLK) ? bsum[t] : 0;
    sb[t] = v;
    __syncthreads();
    for (int off = 1; off < 256; off <<= 1) {
        int a = (t >= off) ? sb[t - off] : 0;
        __syncthreads();
        sb[t] += a;
        __syncthreads();
    }
    int boff = (blockIdx.x == 0) ? 0 : sb[blockIdx.x - 1];
    int i = blockIdx.x * 256 + t;
    if (i < NN) {
        int r = escan[i] + boff;
        rowstart[i] = r;
        cursor[i]   = r;
    }
    if (i == 0) rowstart[NN] = EETOT;
    if (i < NN) {
        int is64 = flags[13];
        int bc = ld_idx(batch, i, is64);
        if (i == 0) {
            for (int g = 0; g <= bc; ++g) gstart[g] = 0;
        } else {
            int bp = ld_idx(batch, i - 1, is64);
            for (int g = bp + 1; g <= bc; ++g) gstart[g] = i;
        }
        if (i == NN - 1) {
            for (int g = bc + 1; g <= NG; ++g) gstart[g] = NN;
        }
    }
}

// ---------- CSR fill with XCD-affinity dst binning ----------
__global__ __launch_bounds__(256) void fill_kernel(const int* ei, const int* flags,
        const float* dinv, int* cursor, unsigned int* cv) {
    int chunk = blockIdx.x >> 3;
    int par   = blockIdx.x & 7;
    int base  = chunk * FEPB;
    int is64  = flags[12];
    #pragma unroll
    for (int k = 0; k < FEPB / 256; ++k) {
        int e = base + k * 256 + threadIdx.x;
        if (e >= EETOT) break;
        int s, d;
        if (e < NE) { d = ld_idx(ei, NE + e, is64); s = -1; }
        else        { s = d = e - NE; }
        if (d / NPXCD != par) continue;
        if (s < 0) s = ld_idx(ei, e, is64);
        int pos = atomicAdd(&cursor[d], 1);
        cv[pos] = (unsigned int)s | ((unsigned int)f2bf(dinv[s] * dinv[d]) << 16);
    }
}

// ---------- MFMA GEMM: C[NN][128] = A[NN][128] @ W[128][128], all bf16 ----------
__global__ __launch_bounds__(256) void gemm_mfma(const unsigned int* __restrict__ A,
        const unsigned int* __restrict__ Wt, unsigned short* __restrict__ C) {
    int wave = threadIdx.x >> 6;
    int lane = threadIdx.x & 63;
    int quad = lane >> 4;
    int l16  = lane & 15;
    int mbase = blockIdx.x * 64 + wave * 16;
    int ra = mbase + l16;
    if (ra >= NN) ra = NN - 1;
    short8 af[4];
    const uint4* Arow = (const uint4*)(A + (size_t)ra * FDH);
    #pragma unroll
    for (int kk = 0; kk < 4; ++kk) {
        uint4 v = Arow[kk * 4 + quad];
        af[kk] = *(short8*)&v;
    }
    #pragma unroll
    for (int nt = 0; nt < 8; ++nt) {
        int n = nt * 16 + l16;
        const uint4* Wrow = (const uint4*)(Wt + (size_t)n * FDH);
        f32x4 acc = {0.f, 0.f, 0.f, 0.f};
        #pragma unroll
        for (int kk = 0; kk < 4; ++kk) {
            uint4 wv = Wrow[kk * 4 + quad];
            short8 bf = *(short8*)&wv;
            acc = __builtin_amdgcn_mfma_f32_16x16x32_bf16(af[kk], bf, acc, 0, 0, 0);
        }
        int row0 = mbase + quad * 4;
        #pragma unroll
        for (int reg = 0; reg < 4; ++reg) {
            int r = row0 + reg;
            if (r < NN) C[(size_t)r * FD + nt * 16 + l16] = f2bf(acc[reg]);
        }
    }
}

// ---------- CSR aggregation (bf16 gather, unroll 8) + bias + relu -> bf16 ----------
__global__ __launch_bounds__(256) void aggregate_kernel(const unsigned int* Hb,
        const unsigned int* cv, const int* rowstart, const float* bias,
        unsigned int* outb) {
    int n = blockIdx.x * 4 + (threadIdx.x >> 6);
    int cp = threadIdx.x & 63;
    if (n >= NN) return;
    int jb = rowstart[n], je = rowstart[n + 1];
    float acc0 = 0.f, acc1 = 0.f;
    int j = jb;
    for (; j + 7 < je; j += 8) {
        unsigned int rr[8], hh[8];
        #pragma unroll
        for (int k = 0; k < 8; ++k) rr[k] = cv[j + k];
        #pragma unroll
        for (int k = 0; k < 8; ++k) hh[k] = Hb[(size_t)(rr[k] & 0xFFFFu) * FDH + cp];
        #pragma unroll
        for (int k = 0; k < 8; ++k) {
            float v = bfbits((unsigned short)(rr[k] >> 16));
            acc0 += v * bflo(hh[k]);
            acc1 += v * bfhi(hh[k]);
        }
    }
    for (; j + 3 < je; j += 4) {
        unsigned int rr[4], hh[4];
        #pragma unroll
        for (int k = 0; k < 4; ++k) rr[k] = cv[j + k];
        #pragma unroll
        for (int k = 0; k < 4; ++k) hh[k] = Hb[(size_t)(rr[k] & 0xFFFFu) * FDH + cp];
        #pragma unroll
        for (int k = 0; k < 4; ++k) {
            float v = bfbits((unsigned short)(rr[k] >> 16));
            acc0 += v * bflo(hh[k]);
            acc1 += v * bfhi(hh[k]);
        }
    }
    for (; j < je; ++j) {
        unsigned int r = cv[j];
        unsigned int h = Hb[(size_t)(r & 0xFFFFu) * FDH + cp];
        float v = bfbits((unsigned short)(r >> 16));
        acc0 += v * bflo(h);
        acc1 += v * bfhi(h);
    }
    acc0 = fmaxf(acc0 + bias[2 * cp], 0.f);
    acc1 = fmaxf(acc1 + bias[2 * cp + 1], 0.f);
    outb[(size_t)n * FDH + cp] = packbf(acc0, acc1);
}

// ---------- pool partials: 8 slices per graph ----------
__global__ __launch_bounds__(64) void pool_part(const unsigned int* Hb,
        const int* gstart, float* part) {
    int g = blockIdx.x >> 3;
    int k = blockIdx.x & (PK - 1);
    int cp = threadIdx.x;
    int s = gstart[g], e = gstart[g + 1];
    int len = e - s;
    int per = (len + PK - 1) / PK;
    int ss = s + k * per;
    int ee = ss + per; if (ee > e) ee = e;
    float a0 = 0.f, a1 = 0.f, b0 = 0.f, b1 = 0.f;
    int n = ss;
    for (; n + 1 < ee; n += 2) {
        unsigned int h0 = Hb[(size_t)n * FDH + cp];
        unsigned int h1 = Hb[(size_t)(n + 1) * FDH + cp];
        a0 += bflo(h0); a1 += bfhi(h0);
        b0 += bflo(h1); b1 += bfhi(h1);
    }
    if (n < ee) {
        unsigned int h0 = Hb[(size_t)n * FDH + cp];
        a0 += bflo(h0); a1 += bfhi(h0);
    }
    part[(size_t)(g * PK + k) * FD + 2 * cp]     = a0 + b0;
    part[(size_t)(g * PK + k) * FD + 2 * cp + 1] = a1 + b1;
}

// ---------- head (+ partial reduce fused) ----------
__global__ __launch_bounds__(128) void head_kernel(const float* part, const int* gstart,
        const float* addf, const float* fc1w, const float* fc1b,
        const float* fc2w, const float* fc2b, const int* flags, void* outp) {
    int g = blockIdx.x;
    int t = threadIdx.x;
    __shared__ float z[FD + FA];
    __shared__ float h[FD];
    float a = 0.f;
    #pragma unroll
    for (int k = 0; k < PK; ++k) a += part[(size_t)(g * PK + k) * FD + t];
    float cnt = (float)(gstart[g + 1] - gstart[g]);
    if (cnt < 1.0f) cnt = 1.0f;
    z[t] = a / cnt;
    if (t < FA) z[FD + t] = addf[g * FA + t];
    __syncthreads();
    float acc = fc1b[t];
    #pragma unroll 4
    for (int k = 0; k < FD + FA; ++k)
        acc += z[k] * fc1w[k * FD + t];
    h[t] = fmaxf(acc, 0.f);
    __syncthreads();
    if (t < 2) {
        float o = fc2b[t];
        for (int j = 0; j < FD; ++j) o += h[j] * fc2w[j * 2 + t];
        if (flags[0]) ((unsigned short*)outp)[g * 2 + t] = f2bf(o);
        else          ((float*)outp)[g * 2 + t] = o;
    }
}

extern "C" void kernel_launch(void* const* d_in, const int* in_sizes, int n_in,
                              void* d_out, int out_size, void* d_ws, size_t ws_size,
                              hipStream_t stream) {
    (void)out_size;

    if (n_in != 12) {
        hipLaunchKernelGGL(mark_kernel, dim3(1), dim3(128), 0, stream,
                           (float*)d_out, 2000.0f);
        return;
    }
    const int exp_sizes[12] = {6400000, 1600000, 50000, 4096, 16384, 128,
                               16384, 128, 20480, 128, 256, 2};
    for (int i = 0; i < 12; ++i) {
        if (in_sizes[i] != exp_sizes[i]) {
            hipLaunchKernelGGL(mark_kernel, dim3(1), dim3(128), 0, stream,
                               (float*)d_out, 3000.0f + 100.0f * i);
            return;
        }
    }

    size_t off = 0;
    char* base = (char*)d_ws;
#define WSALLOC(ptr, type, nbytes) \
    type* ptr = (type*)(base + off); off += (((size_t)(nbytes)) + 255) & ~(size_t)255;
    WSALLOC(bufA,  unsigned int, (size_t)NN * FDH * 4)
    WSALLOC(bufB,  unsigned int, (size_t)NN * FDH * 4)
    WSALLOC(bufC,  unsigned int, (size_t)NN * FDH * 4)
    WSALLOC(dinv,  float, (size_t)NN * 4)
    WSALLOC(degi,  int,   (size_t)NN * 4)
    WSALLOC(rowst, int,   (size_t)(NN + 1) * 4)
    WSALLOC(cursor,int,   (size_t)NN * 4)
    WSALLOC(escan, int,   (size_t)NN * 4)
    WSALLOC(bsum,  int,   (size_t)NBLK * 4)
    WSALLOC(cv,    unsigned int, (size_t)EETOT * 4)
    WSALLOC(part,  float, (size_t)NG * PK * FD * 4)
    WSALLOC(gstart,int,   (size_t)(NG + 1) * 4)
    WSALLOC(W1t,   unsigned int, (size_t)FD * FDH * 4)
    WSALLOC(W2t,   unsigned int, (size_t)FD * FDH * 4)
    WSALLOC(b1f,   float, FD * 4)
    WSALLOC(b2f,   float, FD * 4)
    WSALLOC(addff, float, (size_t)NG * FA * 4)
    WSALLOC(fc1wf, float, (size_t)(FD + FA) * FD * 4)
    WSALLOC(fc1bf, float, FD * 4)
    WSALLOC(fc2wf, float, FD * 2 * 4)
    WSALLOC(fc2bf, float, 2 * 4)
    WSALLOC(flags, int, 16 * 4)
#undef WSALLOC
    if (ws_size < off) {
        hipLaunchKernelGGL(mark_kernel, dim3(1), dim3(128), 0, stream,
                           (float*)d_out, 1000.0f);
        return;
    }

    const int* ei    = (const int*)d_in[1];
    const int* batch = (const int*)d_in[2];

    hipLaunchKernelGGL(flags_kernel, dim3(1), dim3(64), 0, stream,
                       (const unsigned int*)d_in[0], ei, batch,
                       (const unsigned int*)d_in[3], (const unsigned int*)d_in[4],
                       (const unsigned int*)d_in[5], (const unsigned int*)d_in[6],
                       (const unsigned int*)d_in[7], (const unsigned int*)d_in[8],
                       (const unsigned int*)d_in[9], (const unsigned int*)d_in[10],
                       (const unsigned int*)d_in[11], flags);

    hipLaunchKernelGGL(prep, dim3(12859), dim3(256), 0, stream,
                       d_in[0], d_in[3], d_in[4], d_in[5], d_in[6],
                       d_in[7], d_in[8], d_in[9], d_in[10], d_in[11],
                       bufC, W1t, W2t, addff, b1f, b2f, fc1wf, fc1bf,
                       fc2wf, fc2bf, flags, degi);

    hipLaunchKernelGGL(deg_kernel, dim3((NE + 255) / 256), dim3(256), 0, stream,
                       ei, flags, degi);
    hipLaunchKernelGGL(scan1, dim3(NBLK), dim3(256), 0, stream,
                       degi, dinv, escan, bsum);
    hipLaunchKernelGGL(scan3, dim3(NBLK), dim3(256), 0, stream,
                       escan, bsum, batch, flags, rowst, cursor, gstart);
    hipLaunchKernelGGL(fill_kernel, dim3(FNCH * 8), dim3(256), 0, stream,
                       ei, flags, dinv, cursor, cv);

    hipLaunchKernelGGL(gemm_mfma, dim3((NN + 63) / 64), dim3(256), 0, stream,
                       bufC, W1t, (unsigned short*)bufA);
    hipLaunchKernelGGL(aggregate_kernel, dim3((NN + 3) / 4), dim3(256), 0, stream,
                       bufA, cv, rowst, b1f, bufB);
    hipLaunchKernelGGL(gemm_mfma, dim3((NN + 63) / 64), dim3(256), 0, stream,
                       bufB, W2t, (unsigned short*)bufA);
    hipLaunchKernelGGL(aggregate_kernel, dim3((NN + 3) / 4), dim3(256), 0, stream,
                       bufA, cv, rowst, b2f, bufB);

    hipLaunchKernelGGL(pool_part, dim3(NG * PK), dim3(64), 0, stream,
                       bufB, gstart, part);
    hipLaunchKernelGGL(head_kernel, dim3(NG), dim3(FD), 0, stream,
                       part, gstart, addff, fc1wf, fc1bf, fc2wf, fc2bf,
                       flags, d_out);
}